// Round 2
// baseline (12162.377 us; speedup 1.0000x reference)
//
#include <hip/hip_runtime.h>
#include <stdint.h>

// ---------------------------------------------------------------------------
// LSTM time-series predictor, persistent-kernel design.
// B=64, T=512, I=64, H=512, O=64, TGT=96.
// 128 workgroups, each owns 4 hidden units of BOTH layers (all 4 gates).
// Weights (bf16) live in static LDS; cell state c lives in registers.
// Grid-wide sync via monotonic atomic barrier in d_ws.
// Encoder: layer1 pipelined 1 step behind layer0 -> 513 barriers.
// Decoder: 3 phases (layer0 / layer1 / fc+feedback) -> 288 barriers.
//
// R1 fix: A-fragment loads of h were missing the per-lane k-offset quad*8
// (MFMA A layout is A[m=lane&15][k=quad*8+j]) -> all h@W products were wrong.
// ---------------------------------------------------------------------------

#define NWG 128
#define NTH 256

constexpr int Bb = 64, Tt = 512, Ii = 64, Hh = 512, Oo = 64, TGT = 96;
constexpr int HS = Bb * Hh;          // elems in one h buffer copy (64*512)

typedef __attribute__((ext_vector_type(8))) short bf16x8;
typedef __attribute__((ext_vector_type(4))) float f32x4;

__device__ __forceinline__ unsigned short f2bf(float f) {
  union { float f; unsigned u; } v; v.f = f;
  return (unsigned short)((v.u + 0x7fffu + ((v.u >> 16) & 1u)) >> 16);
}
__device__ __forceinline__ float bf2f(unsigned short h) {
  union { unsigned u; float f; } v; v.u = ((unsigned)h) << 16; return v.f;
}
__device__ __forceinline__ float sigm(float x) { return 1.f / (1.f + __expf(-x)); }
__device__ __forceinline__ float tanh_(float x) { return 1.f - 2.f / (__expf(2.f * x) + 1.f); }

// pitches padded +8 bf16 so 16 rows spread across banks (260 words % 32 == 4)
constexpr int PW = 520;   // pitch for K=512 matrices
constexpr int PI = 72;    // pitch for K=64 matrix

struct SMem {
  unsigned short whh0[16 * PW];
  unsigned short wih1[16 * PW];
  unsigned short whh1[16 * PW];
  unsigned short wih0[16 * PI];
  float wfc[512];
  float b0[16];
  float b1[16];
  float bfc;
  float pad[3];
  float gbuf[4 * 16 * 17];   // per-wave 16x17 fp32 gate staging / fc partials
};

__device__ __forceinline__ void gbar(unsigned* cnt, unsigned* flag, unsigned ph) {
  __syncthreads();
  if (threadIdx.x == 0) {
    __threadfence();  // agent-scope: publish our h/x/out writes
    unsigned prev = __hip_atomic_fetch_add(cnt, 1u, __ATOMIC_ACQ_REL, __HIP_MEMORY_SCOPE_AGENT);
    if (prev == ph * NWG + (NWG - 1)) {
      __hip_atomic_store(flag, ph + 1u, __ATOMIC_RELEASE, __HIP_MEMORY_SCOPE_AGENT);
    } else {
      while (__hip_atomic_load(flag, __ATOMIC_ACQUIRE, __HIP_MEMORY_SCOPE_AGENT) < ph + 1u) {
        __builtin_amdgcn_s_sleep(1);
      }
    }
  }
  __syncthreads();
}

#define MFMA __builtin_amdgcn_mfma_f32_16x16x32_bf16

__global__ __launch_bounds__(NTH, 1) void lstm_kernel(
    const float* __restrict__ x,
    const float* __restrict__ Wih0, const float* __restrict__ Whh0,
    const float* __restrict__ bih0, const float* __restrict__ bhh0,
    const float* __restrict__ Wih1, const float* __restrict__ Whh1,
    const float* __restrict__ bih1, const float* __restrict__ bhh1,
    const float* __restrict__ Wfc, const float* __restrict__ bfc,
    unsigned short* h0buf, unsigned short* h1buf, unsigned short* xdec,
    unsigned* bar, float* __restrict__ out)
{
  __shared__ SMem sm;
  const int wg = blockIdx.x;
  const int tid = threadIdx.x;

  // ---- stage weight slices into LDS (fp32 -> bf16), once ----
  // local row n in [0,16): gate g=n>>2 (i,f,g,o), hidden j=n&3
  for (int e = tid; e < 16 * 128; e += NTH) {   // 16 rows x 512 K, 4 elems per e
    int row = e >> 7, c4 = (e & 127) << 2;
    int g = row >> 2, j = row & 3;
    size_t grow = (size_t)(g * 512 + wg * 4 + j);
    float4 a = *(const float4*)(Whh0 + grow * 512 + c4);
    float4 b = *(const float4*)(Wih1 + grow * 512 + c4);
    float4 c = *(const float4*)(Whh1 + grow * 512 + c4);
    int o = row * PW + c4;
    sm.whh0[o] = f2bf(a.x); sm.whh0[o + 1] = f2bf(a.y); sm.whh0[o + 2] = f2bf(a.z); sm.whh0[o + 3] = f2bf(a.w);
    sm.wih1[o] = f2bf(b.x); sm.wih1[o + 1] = f2bf(b.y); sm.wih1[o + 2] = f2bf(b.z); sm.wih1[o + 3] = f2bf(b.w);
    sm.whh1[o] = f2bf(c.x); sm.whh1[o + 1] = f2bf(c.y); sm.whh1[o + 2] = f2bf(c.z); sm.whh1[o + 3] = f2bf(c.w);
  }
  for (int e = tid; e < 16 * 16; e += NTH) {    // W_ih0: 16 rows x 64 K
    int row = e >> 4, c4 = (e & 15) << 2;
    int g = row >> 2, j = row & 3;
    size_t grow = (size_t)(g * 512 + wg * 4 + j);
    float4 a = *(const float4*)(Wih0 + grow * 64 + c4);
    int o = row * PI + c4;
    sm.wih0[o] = f2bf(a.x); sm.wih0[o + 1] = f2bf(a.y); sm.wih0[o + 2] = f2bf(a.z); sm.wih0[o + 3] = f2bf(a.w);
  }
  if (wg < 64) {
    for (int e = tid; e < 512; e += NTH) sm.wfc[e] = Wfc[(size_t)wg * 512 + e];
  }
  if (tid < 16) {
    int g = tid >> 2, j = tid & 3;
    int grow = g * 512 + wg * 4 + j;
    sm.b0[tid] = bih0[grow] + bhh0[grow];
    sm.b1[tid] = bih1[grow] + bhh1[grow];
  }
  if (tid == 0) sm.bfc = (wg < 64) ? bfc[wg] : 0.f;
  __syncthreads();

  // ---- per-lane constants ----
  const int wave = tid >> 6, lane = tid & 63;
  const int col = lane & 15, quad = lane >> 4;
  const int bm = wave * 16;                 // batch base of this wave's M-tile
  const int arow = bm + col;                // batch row this lane loads A-frags for
  const int koff = quad * 8;                // per-lane k offset within a 32-chunk
  const float b0c = sm.b0[col];
  const float b1c = sm.b1[col];
  const unsigned short* pwhh0 = sm.whh0 + col * PW + koff;
  const unsigned short* pwih1 = sm.wih1 + col * PW + koff;
  const unsigned short* pwhh1 = sm.whh1 + col * PW + koff;
  const unsigned short* pwih0 = sm.wih0 + col * PI + koff;
  float* sg = sm.gbuf + wave * (16 * 17);
  unsigned* cnt = bar;
  unsigned* flag = bar + 16;                // separate cache line
  unsigned ph = 0;
  float c0 = 0.f, c1 = 0.f;                 // cell state (this lane's (b,j) pair)
  const size_t xstride = (size_t)Tt * Ii;

  // epilogue: gates -> LDS -> per-(batch,hidden) activations; update c; write h (bf16)
  auto cellout = [&](f32x4 acc, float& cst, unsigned short* hdst) {
#pragma unroll
    for (int r = 0; r < 4; ++r) sg[(quad * 4 + r) * 17 + col] = acc[r];
    // wave-internal LDS exchange; compiler inserts lgkmcnt waits
    int bl = col, j = quad;
    float iv = sigm(sg[bl * 17 + j]);
    float fv = sigm(sg[bl * 17 + 4 + j]);
    float gv = tanh_(sg[bl * 17 + 8 + j]);
    float ov = sigm(sg[bl * 17 + 12 + j]);
    cst = fv * cst + iv * gv;
    float h = ov * tanh_(cst);
    hdst[(size_t)(bm + bl) * 512 + wg * 4 + j] = f2bf(h);
  };

  auto loadx = [&](const float* base, int kc) -> bf16x8 {
    const float* p = base + kc * 32 + koff;
    float4 u = *(const float4*)p;
    float4 v = *(const float4*)(p + 4);
    bf16x8 r;
    r[0] = (short)f2bf(u.x); r[1] = (short)f2bf(u.y); r[2] = (short)f2bf(u.z); r[3] = (short)f2bf(u.w);
    r[4] = (short)f2bf(v.x); r[5] = (short)f2bf(v.y); r[6] = (short)f2bf(v.z); r[7] = (short)f2bf(v.w);
    return r;
  };

  // ================= encoder: t = 0..512, layer1 lags by 1 =================
  for (int t = 0; t <= Tt; ++t) {
    const unsigned short* h0prev = h0buf + ((t + 1) & 1) * HS;  // h0_{t-1}
    unsigned short* h0cur = h0buf + (t & 1) * HS;               // h0_t
    const unsigned short* h1prev = h1buf + (t & 1) * HS;        // h1_{t-2}
    unsigned short* h1cur = h1buf + ((t + 1) & 1) * HS;         // h1_{t-1}
    f32x4 z = {b0c, b0c, b0c, b0c};
    f32x4 y = {b1c, b1c, b1c, b1c};
    if (t < Tt) {
      const float* xb = x + (size_t)arow * xstride + (size_t)t * Ii;
#pragma unroll
      for (int kc = 0; kc < 2; ++kc) {
        bf16x8 a = loadx(xb, kc);
        z = MFMA(a, *(const bf16x8*)(pwih0 + kc * 32), z, 0, 0, 0);
      }
    }
    if (t >= 1) {
      const unsigned short* hp = h0prev + (size_t)arow * 512 + koff;
      if (t < Tt) {
#pragma unroll 4
        for (int kc = 0; kc < 16; ++kc) {
          bf16x8 a = *(const bf16x8*)(hp + kc * 32);   // shared A: layer0-h & layer1-x
          z = MFMA(a, *(const bf16x8*)(pwhh0 + kc * 32), z, 0, 0, 0);
          y = MFMA(a, *(const bf16x8*)(pwih1 + kc * 32), y, 0, 0, 0);
        }
      } else {
#pragma unroll 4
        for (int kc = 0; kc < 16; ++kc) {
          bf16x8 a = *(const bf16x8*)(hp + kc * 32);
          y = MFMA(a, *(const bf16x8*)(pwih1 + kc * 32), y, 0, 0, 0);
        }
      }
      if (t >= 2) {
        const unsigned short* hq = h1prev + (size_t)arow * 512 + koff;
#pragma unroll 4
        for (int kc = 0; kc < 16; ++kc) {
          bf16x8 a = *(const bf16x8*)(hq + kc * 32);
          y = MFMA(a, *(const bf16x8*)(pwhh1 + kc * 32), y, 0, 0, 0);
        }
      }
    }
    if (t < Tt) cellout(z, c0, h0cur);
    if (t >= 1) cellout(y, c1, h1cur);
    gbar(cnt, flag, ph); ++ph;
  }

  // ================= decoder: d = 0..95, 3 phases per step =================
  for (int d = 0; d < TGT; ++d) {
    const unsigned short* h0p = h0buf + ((d + 1) & 1) * HS;
    unsigned short* h0w = h0buf + (d & 1) * HS;
    const unsigned short* h1p = h1buf + ((d + 1) & 1) * HS;
    unsigned short* h1w = h1buf + (d & 1) * HS;

    // ---- phase A: layer0 ----
    {
      f32x4 z = {b0c, b0c, b0c, b0c};
#pragma unroll
      for (int kc = 0; kc < 2; ++kc) {
        bf16x8 a;
        if (d == 0) a = loadx(x + (size_t)arow * xstride + (size_t)(Tt - 1) * Ii, kc);
        else        a = *(const bf16x8*)(xdec + arow * 64 + kc * 32 + koff);
        z = MFMA(a, *(const bf16x8*)(pwih0 + kc * 32), z, 0, 0, 0);
      }
      const unsigned short* hp = h0p + (size_t)arow * 512 + koff;
#pragma unroll 4
      for (int kc = 0; kc < 16; ++kc) {
        bf16x8 a = *(const bf16x8*)(hp + kc * 32);
        z = MFMA(a, *(const bf16x8*)(pwhh0 + kc * 32), z, 0, 0, 0);
      }
      cellout(z, c0, h0w);
    }
    gbar(cnt, flag, ph); ++ph;

    // ---- phase B: layer1 ----
    {
      f32x4 y = {b1c, b1c, b1c, b1c};
      const unsigned short* ha = h0w + (size_t)arow * 512 + koff;  // h0_d (fresh)
      const unsigned short* hb = h1p + (size_t)arow * 512 + koff;  // h1_{d-1}
#pragma unroll 4
      for (int kc = 0; kc < 16; ++kc) {
        bf16x8 a = *(const bf16x8*)(ha + kc * 32);
        y = MFMA(a, *(const bf16x8*)(pwih1 + kc * 32), y, 0, 0, 0);
        bf16x8 a2 = *(const bf16x8*)(hb + kc * 32);
        y = MFMA(a2, *(const bf16x8*)(pwhh1 + kc * 32), y, 0, 0, 0);
      }
      cellout(y, c1, h1w);
    }
    gbar(cnt, flag, ph); ++ph;

    // ---- phase C: fc (y = h1 @ W_fc^T + b_fc), WG k owns output column k ----
    {
      if (wg < 64) {
        int b = tid & 63, ks = tid >> 6;
        const unsigned short* hr = h1w + (size_t)b * 512 + ks * 128;
        float s = 0.f;
#pragma unroll 4
        for (int k = 0; k < 128; k += 8) {
          bf16x8 hv = *(const bf16x8*)(hr + k);
          const float* wp = sm.wfc + ks * 128 + k;
#pragma unroll
          for (int q = 0; q < 8; ++q) s += bf2f((unsigned short)hv[q]) * wp[q];
        }
        sm.gbuf[ks * 64 + b] = s;
      }
      __syncthreads();
      if (wg < 64 && tid < 64) {
        float yv = sm.bfc + sm.gbuf[tid] + sm.gbuf[64 + tid] + sm.gbuf[128 + tid] + sm.gbuf[192 + tid];
        out[(size_t)tid * (TGT * Oo) + d * Oo + wg] = yv;   // (b, d, o=wg)
        xdec[tid * 64 + wg] = f2bf(yv);                     // feedback input
      }
    }
    gbar(cnt, flag, ph); ++ph;
  }
}

extern "C" void kernel_launch(void* const* d_in, const int* in_sizes, int n_in,
                              void* d_out, int out_size, void* d_ws, size_t ws_size,
                              hipStream_t stream) {
  (void)in_sizes; (void)n_in; (void)out_size; (void)ws_size;
  const float* x    = (const float*)d_in[0];
  const float* Wih0 = (const float*)d_in[1];
  const float* Whh0 = (const float*)d_in[2];
  const float* bih0 = (const float*)d_in[3];
  const float* bhh0 = (const float*)d_in[4];
  const float* Wih1 = (const float*)d_in[5];
  const float* Whh1 = (const float*)d_in[6];
  const float* bih1 = (const float*)d_in[7];
  const float* bhh1 = (const float*)d_in[8];
  const float* Wfc  = (const float*)d_in[9];
  const float* bfc  = (const float*)d_in[10];

  char* ws = (char*)d_ws;
  unsigned* bar = (unsigned*)ws;                                   // 256 B (cnt @0, flag @64B)
  unsigned short* h0buf = (unsigned short*)(ws + 256);             // 2*HS*2 = 128 KiB
  unsigned short* h1buf = (unsigned short*)(ws + 256 + 131072);    // 128 KiB
  unsigned short* xdec  = (unsigned short*)(ws + 256 + 262144);    // 8 KiB

  hipMemsetAsync(bar, 0, 256, stream);
  hipLaunchKernelGGL(lstm_kernel, dim3(NWG), dim3(NTH), 0, stream,
                     x, Wih0, Whh0, bih0, bhh0, Wih1, Whh1, bih1, bhh1, Wfc, bfc,
                     h0buf, h1buf, xdec, bar, (float*)d_out);
}

// Round 3
// 6839.334 us; speedup vs baseline: 1.7783x; 1.7783x over previous
//
#include <hip/hip_runtime.h>
#include <stdint.h>

// ---------------------------------------------------------------------------
// LSTM time-series predictor, persistent-kernel, fence-free exchange.
// B=64, T=512, I=64, H=512, O=64, TGT=96.
// 64 WGs, each owns 8 hidden units of BOTH layers (all 4 gates).
// Weights bf16 in LDS (~113KB); cell state in registers.
// All cross-WG data (h0/h1/ybuf/barrier slots) uses RELAXED AGENT atomics
// (sc0/sc1 -> bypass L1/L2 to coherence point) => no buffer_wbl2/inv ever.
// Barrier: per-WG monotonic slot + all-to-all poll by wave 0 (64 lanes).
// h layout: hblk[src_wg][b][j0..7] (16B per (src,b)) -> full-line writes,
// A-fragment reads = two 8B atomic loads.
// Encoder: layer1 lags 1 step -> 513 barriers. Decoder: 3 phases -> 288.
// ---------------------------------------------------------------------------

#define NWG 64
#define NTH 256

constexpr int Bb = 64, Tt = 512, Ii = 64, Hh = 512, Oo = 64, TGT = 96;
constexpr int HS = Bb * Hh;   // elems (ushort) per h time-slot

typedef __attribute__((ext_vector_type(8))) short bf16x8;
typedef __attribute__((ext_vector_type(4))) float f32x4;
typedef unsigned long long u64;

__device__ __forceinline__ unsigned short f2bf(float f) {
  union { float f; unsigned u; } v; v.f = f;
  return (unsigned short)((v.u + 0x7fffu + ((v.u >> 16) & 1u)) >> 16);
}
__device__ __forceinline__ float bf2f(unsigned short h) {
  union { unsigned u; float f; } v; v.u = ((unsigned)h) << 16; return v.f;
}
__device__ __forceinline__ float sigm(float x) { return 1.f / (1.f + __expf(-x)); }
__device__ __forceinline__ float tanh_(float x) { return 1.f - 2.f / (__expf(2.f * x) + 1.f); }

__device__ __forceinline__ u64 ald(const u64* p) {
  return __hip_atomic_load(p, __ATOMIC_RELAXED, __HIP_MEMORY_SCOPE_AGENT);
}
__device__ __forceinline__ void ast(u64* p, u64 v) {
  __hip_atomic_store(p, v, __ATOMIC_RELAXED, __HIP_MEMORY_SCOPE_AGENT);
}
__device__ __forceinline__ float aldf(const float* p) {
  return __hip_atomic_load(p, __ATOMIC_RELAXED, __HIP_MEMORY_SCOPE_AGENT);
}
__device__ __forceinline__ void astf(float* p, float v) {
  __hip_atomic_store(p, v, __ATOMIC_RELAXED, __HIP_MEMORY_SCOPE_AGENT);
}

constexpr int PW = 520;   // LDS pitch (ushort) for K=512 weight rows
constexpr int PI = 72;    // LDS pitch for K=64

struct SMem {
  unsigned short whh0[32 * PW];
  unsigned short wih1[32 * PW];
  unsigned short whh1[32 * PW];
  unsigned short wih0[32 * PI];
  float wfc[512];
  float b0[32];
  float b1[32];
  float bfcv;
  float gbuf[4 * 16 * 17];          // per-wave D staging; fc partials reuse [0..255]
  unsigned short hstage[4 * 16 * 8];// per-wave h pack staging
};

// fence-free all-to-all grid barrier (NWG == 64 == wave width)
__device__ __forceinline__ void gbar(unsigned* slots, unsigned tgt) {
  __syncthreads();                      // compiler drains vmcnt per wave here
  asm volatile("" ::: "memory");
  if (threadIdx.x < 64) {
    if (threadIdx.x == 0)
      __hip_atomic_store(slots + blockIdx.x, tgt, __ATOMIC_RELAXED, __HIP_MEMORY_SCOPE_AGENT);
    while (true) {
      unsigned v = __hip_atomic_load(slots + threadIdx.x, __ATOMIC_RELAXED, __HIP_MEMORY_SCOPE_AGENT);
      if (__all((int)(v >= tgt))) break;
      __builtin_amdgcn_s_sleep(1);
    }
  }
  asm volatile("" ::: "memory");
  __syncthreads();
}

#define MFMA __builtin_amdgcn_mfma_f32_16x16x32_bf16

__global__ __launch_bounds__(NTH, 1) void lstm_kernel(
    const float* __restrict__ x,
    const float* __restrict__ Wih0, const float* __restrict__ Whh0,
    const float* __restrict__ bih0, const float* __restrict__ bhh0,
    const float* __restrict__ Wih1, const float* __restrict__ Whh1,
    const float* __restrict__ bih1, const float* __restrict__ bhh1,
    const float* __restrict__ Wfc, const float* __restrict__ bfc,
    unsigned short* h0buf, unsigned short* h1buf, float* ybuf,
    unsigned* slots, float* __restrict__ out)
{
  __shared__ SMem sm;
  const int wg = blockIdx.x;
  const int tid = threadIdx.x;

  // ---- stage weight slices into LDS (fp32 -> bf16), once ----
  // LDS row r in [0,32): j = r>>2 (hidden-local), g = r&3 (gate i,f,g,o)
  for (int e = tid; e < 32 * 128; e += NTH) {   // 32 rows x 512 K, 4 elems each
    int row = e >> 7, c4 = (e & 127) << 2;
    int j = row >> 2, g = row & 3;
    size_t grow = (size_t)(g * 512 + wg * 8 + j);
    float4 a = *(const float4*)(Whh0 + grow * 512 + c4);
    float4 b = *(const float4*)(Wih1 + grow * 512 + c4);
    float4 c = *(const float4*)(Whh1 + grow * 512 + c4);
    int o = row * PW + c4;
    sm.whh0[o] = f2bf(a.x); sm.whh0[o + 1] = f2bf(a.y); sm.whh0[o + 2] = f2bf(a.z); sm.whh0[o + 3] = f2bf(a.w);
    sm.wih1[o] = f2bf(b.x); sm.wih1[o + 1] = f2bf(b.y); sm.wih1[o + 2] = f2bf(b.z); sm.wih1[o + 3] = f2bf(b.w);
    sm.whh1[o] = f2bf(c.x); sm.whh1[o + 1] = f2bf(c.y); sm.whh1[o + 2] = f2bf(c.z); sm.whh1[o + 3] = f2bf(c.w);
  }
  for (int e = tid; e < 32 * 16; e += NTH) {    // W_ih0: 32 rows x 64 K
    int row = e >> 4, c4 = (e & 15) << 2;
    int j = row >> 2, g = row & 3;
    size_t grow = (size_t)(g * 512 + wg * 8 + j);
    float4 a = *(const float4*)(Wih0 + grow * 64 + c4);
    int o = row * PI + c4;
    sm.wih0[o] = f2bf(a.x); sm.wih0[o + 1] = f2bf(a.y); sm.wih0[o + 2] = f2bf(a.z); sm.wih0[o + 3] = f2bf(a.w);
  }
  for (int e = tid; e < 512; e += NTH) sm.wfc[e] = Wfc[(size_t)wg * 512 + e];
  if (tid < 32) {
    int j = tid >> 2, g = tid & 3;
    int grow = g * 512 + wg * 8 + j;
    sm.b0[tid] = bih0[grow] + bhh0[grow];
    sm.b1[tid] = bih1[grow] + bhh1[grow];
  }
  if (tid == 0) sm.bfcv = bfc[wg];
  __syncthreads();

  // ---- per-lane constants ----
  const int wave = tid >> 6, lane = tid & 63;
  const int col = lane & 15, quad = lane >> 4;
  const int bm = wave * 16;                 // batch base of this wave's M-tile
  const int arow = bm + col;                // batch row for A-fragments
  const int koff = quad * 8;                // per-lane k offset in a 32-chunk
  const int qoff = quad * 128 + arow * 2;   // u64 index into h slot (+kc*512)
  const float b0c0 = sm.b0[col],      b0c1 = sm.b0[16 + col];
  const float b1c0 = sm.b1[col],      b1c1 = sm.b1[16 + col];
  const unsigned short* pwhh0 = sm.whh0 + col * PW + koff;
  const unsigned short* pwih1 = sm.wih1 + col * PW + koff;
  const unsigned short* pwhh1 = sm.whh1 + col * PW + koff;
  const unsigned short* pwih0 = sm.wih0 + col * PI + koff;
  float* sg = sm.gbuf + wave * (16 * 17);
  unsigned short* hs_ = sm.hstage + wave * (16 * 8);
  unsigned ph = 0;
  float c0t[2] = {0.f, 0.f}, c1t[2] = {0.f, 0.f};
  const size_t xstride = (size_t)Tt * Ii;

  auto hfrag = [&](const u64* hq, int kc) -> bf16x8 {
    union { u64 q[2]; bf16x8 v; } u;
    u.q[0] = ald(hq + kc * 512);
    u.q[1] = ald(hq + kc * 512 + 1);
    return u.v;
  };

  auto loadx = [&](const float* p) -> bf16x8 {
    float4 u = *(const float4*)p;
    float4 v = *(const float4*)(p + 4);
    bf16x8 r;
    r[0] = (short)f2bf(u.x); r[1] = (short)f2bf(u.y); r[2] = (short)f2bf(u.z); r[3] = (short)f2bf(u.w);
    r[4] = (short)f2bf(v.x); r[5] = (short)f2bf(v.y); r[6] = (short)f2bf(v.z); r[7] = (short)f2bf(v.w);
    return r;
  };

  // epilogue for one layer, both 16-col tiles; writes h slice (bypass stores)
  auto cellout = [&](f32x4 acc0, f32x4 acc1, float* cst, unsigned short* hdst) {
#pragma unroll
    for (int t = 0; t < 2; ++t) {
      f32x4 acc = t ? acc1 : acc0;
#pragma unroll
      for (int r = 0; r < 4; ++r) sg[(quad * 4 + r) * 17 + col] = acc[r];
      int bl = lane >> 2, jl = lane & 3;      // 16 batches x 4 hidden-local
      float gi = sg[bl * 17 + jl * 4 + 0];
      float gf = sg[bl * 17 + jl * 4 + 1];
      float gg = sg[bl * 17 + jl * 4 + 2];
      float go = sg[bl * 17 + jl * 4 + 3];
      float iv = sigm(gi), fv = sigm(gf), gv = tanh_(gg), ov = sigm(go);
      float c = fv * cst[t] + iv * gv; cst[t] = c;
      float h = ov * tanh_(c);
      hs_[bl * 8 + t * 4 + jl] = f2bf(h);
    }
    if (lane < 32) {                          // pack 2x 8B per batch row
      int b = lane >> 1, half = lane & 1;
      union { unsigned short s[4]; u64 q; } pk;
#pragma unroll
      for (int i = 0; i < 4; ++i) pk.s[i] = hs_[b * 8 + half * 4 + i];
      ast((u64*)hdst + (size_t)(wg * 64 + bm + b) * 2 + half, pk.q);
    }
  };

  // ================= encoder: t = 0..512, layer1 lags by 1 =================
  for (int t = 0; t <= Tt; ++t) {
    const unsigned short* h0prev = h0buf + ((t + 1) & 1) * HS;
    unsigned short* h0cur = h0buf + (t & 1) * HS;
    const unsigned short* h1prev = h1buf + (t & 1) * HS;
    unsigned short* h1cur = h1buf + ((t + 1) & 1) * HS;
    f32x4 z0 = {b0c0, b0c0, b0c0, b0c0}, z1 = {b0c1, b0c1, b0c1, b0c1};
    f32x4 y0 = {b1c0, b1c0, b1c0, b1c0}, y1 = {b1c1, b1c1, b1c1, b1c1};
    if (t < Tt) {
      const float* xb = x + (size_t)arow * xstride + (size_t)t * Ii + koff;
#pragma unroll
      for (int kc = 0; kc < 2; ++kc) {
        bf16x8 a = loadx(xb + kc * 32);
        z0 = MFMA(a, *(const bf16x8*)(pwih0 + kc * 32), z0, 0, 0, 0);
        z1 = MFMA(a, *(const bf16x8*)(pwih0 + 16 * PI + kc * 32), z1, 0, 0, 0);
      }
    }
    if (t >= 1) {
      const u64* hq = (const u64*)h0prev + qoff;
      if (t < Tt) {
#pragma unroll
        for (int kc = 0; kc < 16; ++kc) {
          bf16x8 a = hfrag(hq, kc);            // shared A: layer0-h & layer1-x
          z0 = MFMA(a, *(const bf16x8*)(pwhh0 + kc * 32), z0, 0, 0, 0);
          z1 = MFMA(a, *(const bf16x8*)(pwhh0 + 16 * PW + kc * 32), z1, 0, 0, 0);
          y0 = MFMA(a, *(const bf16x8*)(pwih1 + kc * 32), y0, 0, 0, 0);
          y1 = MFMA(a, *(const bf16x8*)(pwih1 + 16 * PW + kc * 32), y1, 0, 0, 0);
        }
      } else {
#pragma unroll
        for (int kc = 0; kc < 16; ++kc) {
          bf16x8 a = hfrag(hq, kc);
          y0 = MFMA(a, *(const bf16x8*)(pwih1 + kc * 32), y0, 0, 0, 0);
          y1 = MFMA(a, *(const bf16x8*)(pwih1 + 16 * PW + kc * 32), y1, 0, 0, 0);
        }
      }
      if (t >= 2) {
        const u64* hq1 = (const u64*)h1prev + qoff;
#pragma unroll
        for (int kc = 0; kc < 16; ++kc) {
          bf16x8 a = hfrag(hq1, kc);
          y0 = MFMA(a, *(const bf16x8*)(pwhh1 + kc * 32), y0, 0, 0, 0);
          y1 = MFMA(a, *(const bf16x8*)(pwhh1 + 16 * PW + kc * 32), y1, 0, 0, 0);
        }
      }
    }
    if (t < Tt) cellout(z0, z1, c0t, h0cur);
    if (t >= 1) cellout(y0, y1, c1t, h1cur);
    gbar(slots, ++ph);
  }

  // ================= decoder: d = 0..95, 3 phases per step =================
  for (int d = 0; d < TGT; ++d) {
    const unsigned short* h0p = h0buf + ((d + 1) & 1) * HS;
    unsigned short* h0w = h0buf + (d & 1) * HS;
    const unsigned short* h1p = h1buf + ((d + 1) & 1) * HS;
    unsigned short* h1w = h1buf + (d & 1) * HS;

    // ---- phase A: layer0 ----
    {
      f32x4 z0 = {b0c0, b0c0, b0c0, b0c0}, z1 = {b0c1, b0c1, b0c1, b0c1};
      if (d == 0) {
        const float* xb = x + (size_t)arow * xstride + (size_t)(Tt - 1) * Ii + koff;
#pragma unroll
        for (int kc = 0; kc < 2; ++kc) {
          bf16x8 a = loadx(xb + kc * 32);
          z0 = MFMA(a, *(const bf16x8*)(pwih0 + kc * 32), z0, 0, 0, 0);
          z1 = MFMA(a, *(const bf16x8*)(pwih0 + 16 * PI + kc * 32), z1, 0, 0, 0);
        }
      } else {
        const float* yb = ybuf + arow * 64 + koff;
#pragma unroll
        for (int kc = 0; kc < 2; ++kc) {
          bf16x8 a;
#pragma unroll
          for (int i = 0; i < 8; ++i) a[i] = (short)f2bf(aldf(yb + kc * 32 + i));
          z0 = MFMA(a, *(const bf16x8*)(pwih0 + kc * 32), z0, 0, 0, 0);
          z1 = MFMA(a, *(const bf16x8*)(pwih0 + 16 * PI + kc * 32), z1, 0, 0, 0);
        }
      }
      const u64* hq = (const u64*)h0p + qoff;
#pragma unroll
      for (int kc = 0; kc < 16; ++kc) {
        bf16x8 a = hfrag(hq, kc);
        z0 = MFMA(a, *(const bf16x8*)(pwhh0 + kc * 32), z0, 0, 0, 0);
        z1 = MFMA(a, *(const bf16x8*)(pwhh0 + 16 * PW + kc * 32), z1, 0, 0, 0);
      }
      cellout(z0, z1, c0t, h0w);
    }
    gbar(slots, ++ph);

    // ---- phase B: layer1 ----
    {
      f32x4 y0 = {b1c0, b1c0, b1c0, b1c0}, y1 = {b1c1, b1c1, b1c1, b1c1};
      const u64* ha = (const u64*)h0w + qoff;   // h0_d (fresh)
      const u64* hb = (const u64*)h1p + qoff;   // h1_{d-1}
#pragma unroll
      for (int kc = 0; kc < 16; ++kc) {
        bf16x8 a = hfrag(ha, kc);
        y0 = MFMA(a, *(const bf16x8*)(pwih1 + kc * 32), y0, 0, 0, 0);
        y1 = MFMA(a, *(const bf16x8*)(pwih1 + 16 * PW + kc * 32), y1, 0, 0, 0);
        bf16x8 a2 = hfrag(hb, kc);
        y0 = MFMA(a2, *(const bf16x8*)(pwhh1 + kc * 32), y0, 0, 0, 0);
        y1 = MFMA(a2, *(const bf16x8*)(pwhh1 + 16 * PW + kc * 32), y1, 0, 0, 0);
      }
      cellout(y0, y1, c1t, h1w);
    }
    gbar(slots, ++ph);

    // ---- phase C: fc (y = h1 @ W_fc^T + b_fc); WG owns output col wg ----
    {
      int b = tid & 63, ks = tid >> 6;
      const u64* q = (const u64*)h1w + b * 2;
      float s = 0.f;
#pragma unroll
      for (int si = 0; si < 16; ++si) {
        int src = ks * 16 + si;
        union { u64 q2[2]; unsigned short s8[8]; } u;
        u.q2[0] = ald(q + src * 128);
        u.q2[1] = ald(q + src * 128 + 1);
        const float* wp = sm.wfc + src * 8;
#pragma unroll
        for (int j = 0; j < 8; ++j) s += bf2f(u.s8[j]) * wp[j];
      }
      sm.gbuf[ks * 64 + b] = s;
      __syncthreads();
      if (tid < 64) {
        float yv = sm.bfcv + sm.gbuf[tid] + sm.gbuf[64 + tid] + sm.gbuf[128 + tid] + sm.gbuf[192 + tid];
        out[(size_t)tid * (TGT * Oo) + d * Oo + wg] = yv;   // (b=tid, d, o=wg)
        astf(ybuf + tid * 64 + wg, yv);                     // feedback (fp32)
      }
    }
    gbar(slots, ++ph);
  }
}

extern "C" void kernel_launch(void* const* d_in, const int* in_sizes, int n_in,
                              void* d_out, int out_size, void* d_ws, size_t ws_size,
                              hipStream_t stream) {
  (void)in_sizes; (void)n_in; (void)out_size; (void)ws_size;
  const float* x    = (const float*)d_in[0];
  const float* Wih0 = (const float*)d_in[1];
  const float* Whh0 = (const float*)d_in[2];
  const float* bih0 = (const float*)d_in[3];
  const float* bhh0 = (const float*)d_in[4];
  const float* Wih1 = (const float*)d_in[5];
  const float* Whh1 = (const float*)d_in[6];
  const float* bih1 = (const float*)d_in[7];
  const float* bhh1 = (const float*)d_in[8];
  const float* Wfc  = (const float*)d_in[9];
  const float* bfc  = (const float*)d_in[10];

  char* ws = (char*)d_ws;
  unsigned* slots = (unsigned*)ws;                                  // 512 B
  unsigned short* h0buf = (unsigned short*)(ws + 512);              // 128 KiB (2 slots)
  unsigned short* h1buf = (unsigned short*)(ws + 512 + 131072);     // 128 KiB
  float* ybuf = (float*)(ws + 512 + 262144);                        // 16 KiB

  hipMemsetAsync(slots, 0, 512, stream);
  hipLaunchKernelGGL(lstm_kernel, dim3(NWG), dim3(NTH), 0, stream,
                     x, Wih0, Whh0, bih0, bhh0, Wih1, Whh1, bih1, bhh1, Wfc, bfc,
                     h0buf, h1buf, ybuf, slots, (float*)d_out);
}

// Round 4
// 4252.266 us; speedup vs baseline: 2.8602x; 1.6084x over previous
//
#include <hip/hip_runtime.h>
#include <stdint.h>

// ---------------------------------------------------------------------------
// LSTM time-series predictor, persistent kernel, R4 structure:
// 8 independent batch-groups x 32 WGs. Each WG: 16 hidden units of both
// layers for its group's 8 batches. W_hh0/W_ih1 bf16 in LDS; W_hh1/W_ih0
// fragments in VGPRs. Group h (8KB/matrix) cooperatively staged into LDS
// via bulk relaxed-agent loads (single latency exposure), A-frags via
// ds_read_b128. Barrier scope = 32 WGs, one 128B slot line per group;
// groups fully independent (encoder AND decoder).
// Encoder: layer1 lags 1 step -> 513 barriers. Decoder: 3 phases -> 288.
// ---------------------------------------------------------------------------

#define NWG 256
#define NTH 256

constexpr int Tt = 512, TGT = 96;
constexpr int PW = 520;            // LDS pitch (ushort) for K=512 rows (+8 pad)

typedef __attribute__((ext_vector_type(8))) short bf16x8;
typedef __attribute__((ext_vector_type(4))) float f32x4;
typedef unsigned long long u64;

__device__ __forceinline__ unsigned short f2bf(float f) {
  union { float f; unsigned u; } v; v.f = f;
  return (unsigned short)((v.u + 0x7fffu + ((v.u >> 16) & 1u)) >> 16);
}
__device__ __forceinline__ float bf2f(unsigned short h) {
  union { unsigned u; float f; } v; v.u = ((unsigned)h) << 16; return v.f;
}
__device__ __forceinline__ float sigm(float x) { return 1.f / (1.f + __expf(-x)); }
__device__ __forceinline__ float tanh_(float x) { return 1.f - 2.f / (__expf(2.f * x) + 1.f); }

__device__ __forceinline__ u64 ald(const u64* p) {
  return __hip_atomic_load(p, __ATOMIC_RELAXED, __HIP_MEMORY_SCOPE_AGENT);
}
__device__ __forceinline__ void ast(u64* p, u64 v) {
  __hip_atomic_store(p, v, __ATOMIC_RELAXED, __HIP_MEMORY_SCOPE_AGENT);
}
__device__ __forceinline__ float aldf(const float* p) {
  return __hip_atomic_load(p, __ATOMIC_RELAXED, __HIP_MEMORY_SCOPE_AGENT);
}
__device__ __forceinline__ void astf(float* p, float v) {
  __hip_atomic_store(p, v, __ATOMIC_RELAXED, __HIP_MEMORY_SCOPE_AGENT);
}

struct SMem {
  unsigned short whh0[64 * PW];   // 66.6 KB  rows r: hidden jj=r>>2, gate g=r&3
  unsigned short wih1[64 * PW];   // 66.6 KB
  unsigned short a0[8 * PW];      // 8.3 KB   staged h (A operand), per batch row
  unsigned short a1[8 * PW];      // 8.3 KB
  unsigned short wfc2[2 * 512];   // 2 KB     fc rows w*2, w*2+1 (bf16)
  float gpart[4][272];            // 4.35 KB  per-wave D staging; fc partials alias
  float b0s[64], b1s[64];
  float bfc2[2];
};                                 // ~157 KB < 160 KB

// all-to-all barrier, scope = 32 WGs of one group (one 128B line of slots)
__device__ __forceinline__ void gbar(unsigned* slots, int g, int w, unsigned tgt) {
  __syncthreads();                 // drains vmcnt -> h stores at coherence point
  if (threadIdx.x == 0)
    __hip_atomic_store(slots + g * 32 + w, tgt, __ATOMIC_RELAXED, __HIP_MEMORY_SCOPE_AGENT);
  if (threadIdx.x < 64) {
    const unsigned* sp = slots + g * 32 + (threadIdx.x & 31);
    while (true) {
      unsigned v = __hip_atomic_load(sp, __ATOMIC_RELAXED, __HIP_MEMORY_SCOPE_AGENT);
      if (__all((int)(v >= tgt))) break;
      __builtin_amdgcn_s_sleep(1);
    }
  }
  __syncthreads();
}

#define MFMA(a, b, c) __builtin_amdgcn_mfma_f32_16x16x32_bf16(a, b, c, 0, 0, 0)

__global__ __launch_bounds__(NTH, 1) void lstm_kernel(
    const float* __restrict__ x,
    const float* __restrict__ Wih0, const float* __restrict__ Whh0,
    const float* __restrict__ bih0, const float* __restrict__ bhh0,
    const float* __restrict__ Wih1, const float* __restrict__ Whh1,
    const float* __restrict__ bih1, const float* __restrict__ bhh1,
    const float* __restrict__ Wfc, const float* __restrict__ bfc,
    u64* h0q, u64* h1q, float* ybuf,
    unsigned* slots, float* __restrict__ out)
{
  __shared__ SMem sm;
  const int g = blockIdx.x & 7;    // batch group (8 batches)
  const int w = blockIdx.x >> 3;   // WG within group (16 hidden units)
  const int tid = threadIdx.x;

  // ---- stage W_hh0 / W_ih1 slices into LDS (fp32 -> bf16), once ----
  for (int e = tid; e < 64 * 128; e += NTH) {   // 64 rows x 512 K, 4 elems each
    int row = e >> 7, c4 = (e & 127) << 2;
    int jj = row >> 2, g4 = row & 3;
    size_t grow = (size_t)(g4 * 512 + w * 16 + jj);
    float4 a = *(const float4*)(Whh0 + grow * 512 + c4);
    float4 b = *(const float4*)(Wih1 + grow * 512 + c4);
    int o = row * PW + c4;
    sm.whh0[o] = f2bf(a.x); sm.whh0[o + 1] = f2bf(a.y); sm.whh0[o + 2] = f2bf(a.z); sm.whh0[o + 3] = f2bf(a.w);
    sm.wih1[o] = f2bf(b.x); sm.wih1[o + 1] = f2bf(b.y); sm.wih1[o + 2] = f2bf(b.z); sm.wih1[o + 3] = f2bf(b.w);
  }
  for (int e = tid; e < 1024; e += NTH) {       // fc rows w*2, w*2+1 -> bf16
    int c = e >> 9, k = e & 511;
    sm.wfc2[e] = f2bf(Wfc[(size_t)(w * 2 + c) * 512 + k]);
  }
  if (tid < 64) {
    int jj = tid >> 2, g4 = tid & 3;
    int grow = g4 * 512 + w * 16 + jj;
    sm.b0s[tid] = bih0[grow] + bhh0[grow];
    sm.b1s[tid] = bih1[grow] + bhh1[grow];
  }
  if (tid < 2) sm.bfc2[tid] = bfc[w * 2 + tid];

  // ---- per-lane constants ----
  const int wave = tid >> 6, lane = tid & 63;
  const int col = lane & 15, quad = lane >> 4;
  const int koff = quad * 8;
  const int ab = (col & 7) * PW + koff;        // A-frag base in staged LDS (+kc*32)

  // ---- register-resident W_hh1 / W_ih0 B-fragments (this wave's tile) ----
  // tile n=col -> local row wave*16+col: jj = wave*4 + (col>>2), gate = col&3
  const size_t rowg = (size_t)((col & 3) * 512 + w * 16 + wave * 4 + (col >> 2));
  bf16x8 whh1f[16];
#pragma unroll
  for (int kc = 0; kc < 16; ++kc) {
    const float* p = Whh1 + rowg * 512 + kc * 32 + koff;
    float4 u = *(const float4*)p, v = *(const float4*)(p + 4);
    bf16x8 r;
    r[0] = (short)f2bf(u.x); r[1] = (short)f2bf(u.y); r[2] = (short)f2bf(u.z); r[3] = (short)f2bf(u.w);
    r[4] = (short)f2bf(v.x); r[5] = (short)f2bf(v.y); r[6] = (short)f2bf(v.z); r[7] = (short)f2bf(v.w);
    whh1f[kc] = r;
  }
  bf16x8 wih0f[2];
#pragma unroll
  for (int kc = 0; kc < 2; ++kc) {
    const float* p = Wih0 + rowg * 64 + kc * 32 + koff;
    float4 u = *(const float4*)p, v = *(const float4*)(p + 4);
    bf16x8 r;
    r[0] = (short)f2bf(u.x); r[1] = (short)f2bf(u.y); r[2] = (short)f2bf(u.z); r[3] = (short)f2bf(u.w);
    r[4] = (short)f2bf(v.x); r[5] = (short)f2bf(v.y); r[6] = (short)f2bf(v.z); r[7] = (short)f2bf(v.w);
    wih0f[kc] = r;
  }
  __syncthreads();

  const float b0c = sm.b0s[wave * 16 + col];
  const float b1c = sm.b1s[wave * 16 + col];
  const unsigned short* pwhh0 = sm.whh0 + (wave * 16 + col) * PW + koff;
  const unsigned short* pwih1 = sm.wih1 + (wave * 16 + col) * PW + koff;
  float c0 = 0.f, c1 = 0.f;                     // cell state: lane<32 = (b=lane>>2, j=lane&3)
  unsigned ph = 0;
  const size_t xstride = (size_t)Tt * 64;

  // cooperative sc-load of group's h (1024 u64 = 8KB) into padded LDS
  auto stage = [&](unsigned short* dst, const u64* src) {
#pragma unroll
    for (int i = 0; i < 4; ++i) {
      int idx = tid + i * 256;
      u64 v = ald(src + idx);
      *(u64*)(dst + (idx >> 7) * PW + (idx & 127) * 4) = v;
    }
  };

  auto loadx = [&](const float* p) -> bf16x8 {
    float4 u = *(const float4*)p, v = *(const float4*)(p + 4);
    bf16x8 r;
    r[0] = (short)f2bf(u.x); r[1] = (short)f2bf(u.y); r[2] = (short)f2bf(u.z); r[3] = (short)f2bf(u.w);
    r[4] = (short)f2bf(v.x); r[5] = (short)f2bf(v.y); r[6] = (short)f2bf(v.z); r[7] = (short)f2bf(v.w);
    return r;
  };

  // D -> activations -> c update -> packed h store (wave-local exchange)
  auto actstore = [&](f32x4 v, float& cst, u64* hdst) {
    float* gp = sm.gpart[wave];
#pragma unroll
    for (int r = 0; r < 4; ++r) gp[(quad * 4 + r) * 17 + col] = v[r];
    unsigned hbits = 0;
    int b = lane >> 2, j = lane & 3;
    if (lane < 32) {
      const float* ro = gp + b * 17 + j * 4;
      float iv = sigm(ro[0]), fv = sigm(ro[1]), gv = tanh_(ro[2]), ov = sigm(ro[3]);
      float c = fv * cst + iv * gv; cst = c;
      hbits = f2bf(ov * tanh_(c));
    }
    unsigned h1b = __shfl(hbits, (lane + 1) & 63);
    unsigned h2b = __shfl(hbits, (lane + 2) & 63);
    unsigned h3b = __shfl(hbits, (lane + 3) & 63);
    if (lane < 32 && j == 0) {
      u64 pk = (u64)hbits | ((u64)h1b << 16) | ((u64)h2b << 32) | ((u64)h3b << 48);
      ast(hdst + b * 128 + w * 4 + wave, pk);    // h[b][k=w*16+wave*4 .. +4]
    }
  };

  // ================= encoder: t = 0..512, layer1 lags by 1 =================
  for (int t = 0; t <= Tt; ++t) {
    const u64* h0prev = h0q + ((t + 1) & 1) * 8192 + g * 1024;
    u64* h0cur = h0q + (t & 1) * 8192 + g * 1024;
    const u64* h1prev = h1q + (t & 1) * 8192 + g * 1024;
    u64* h1cur = h1q + ((t + 1) & 1) * 8192 + g * 1024;

    bf16x8 xa0, xa1;
    if (t < Tt) {                                 // x loads early (plain cached)
      const float* xb = x + (size_t)(g * 8 + (col & 7)) * xstride + (size_t)t * 64 + koff;
      xa0 = loadx(xb); xa1 = loadx(xb + 32);
    }
    if (t >= 1) {
      stage(sm.a0, h0prev);
      if (t >= 2) stage(sm.a1, h1prev);
      __syncthreads();
    }
    if (t < Tt) {
      f32x4 za = {b0c, b0c, b0c, b0c}, zb = {0.f, 0.f, 0.f, 0.f};
      za = MFMA(xa0, wih0f[0], za);
      zb = MFMA(xa1, wih0f[1], zb);
      if (t >= 1) {
        f32x4 ya = {b1c, b1c, b1c, b1c}, yb = {0.f, 0.f, 0.f, 0.f};
#pragma unroll
        for (int kc = 0; kc < 16; ++kc) {
          bf16x8 a = *(const bf16x8*)(sm.a0 + ab + kc * 32);   // shared A
          if (kc & 1) { zb = MFMA(a, *(const bf16x8*)(pwhh0 + kc * 32), zb);
                        yb = MFMA(a, *(const bf16x8*)(pwih1 + kc * 32), yb); }
          else        { za = MFMA(a, *(const bf16x8*)(pwhh0 + kc * 32), za);
                        ya = MFMA(a, *(const bf16x8*)(pwih1 + kc * 32), ya); }
        }
        if (t >= 2) {
#pragma unroll
          for (int kc = 0; kc < 16; ++kc) {
            bf16x8 a = *(const bf16x8*)(sm.a1 + ab + kc * 32);
            if (kc & 1) yb = MFMA(a, whh1f[kc], yb);
            else        ya = MFMA(a, whh1f[kc], ya);
          }
        }
        actstore(za + zb, c0, h0cur);
        actstore(ya + yb, c1, h1cur);
      } else {
        actstore(za + zb, c0, h0cur);
      }
    } else {                                      // t == Tt: final layer1 step
      f32x4 ya = {b1c, b1c, b1c, b1c}, yb = {0.f, 0.f, 0.f, 0.f};
#pragma unroll
      for (int kc = 0; kc < 16; ++kc) {
        bf16x8 a = *(const bf16x8*)(sm.a0 + ab + kc * 32);
        if (kc & 1) yb = MFMA(a, *(const bf16x8*)(pwih1 + kc * 32), yb);
        else        ya = MFMA(a, *(const bf16x8*)(pwih1 + kc * 32), ya);
      }
#pragma unroll
      for (int kc = 0; kc < 16; ++kc) {
        bf16x8 a = *(const bf16x8*)(sm.a1 + ab + kc * 32);
        if (kc & 1) yb = MFMA(a, whh1f[kc], yb);
        else        ya = MFMA(a, whh1f[kc], ya);
      }
      actstore(ya + yb, c1, h1cur);
    }
    gbar(slots, g, w, ++ph);
  }

  // ================= decoder: d = 0..95, 3 phases per step =================
  for (int d = 0; d < TGT; ++d) {
    const u64* h0p = h0q + ((d + 1) & 1) * 8192 + g * 1024;
    u64* h0w = h0q + (d & 1) * 8192 + g * 1024;
    const u64* h1p = h1q + ((d + 1) & 1) * 8192 + g * 1024;
    u64* h1w = h1q + (d & 1) * 8192 + g * 1024;

    // ---- phase A: layer0 ----
    {
      bf16x8 xa0, xa1;
      if (d == 0) {
        const float* xb = x + (size_t)(g * 8 + (col & 7)) * xstride + (size_t)(Tt - 1) * 64 + koff;
        xa0 = loadx(xb); xa1 = loadx(xb + 32);
      } else {
        const float* yb = ybuf + g * 512 + (col & 7) * 64 + koff;
        bf16x8 r0, r1;
#pragma unroll
        for (int i = 0; i < 8; ++i) { r0[i] = (short)f2bf(aldf(yb + i)); r1[i] = (short)f2bf(aldf(yb + 32 + i)); }
        xa0 = r0; xa1 = r1;
      }
      stage(sm.a0, h0p);
      __syncthreads();
      f32x4 za = {b0c, b0c, b0c, b0c}, zb = {0.f, 0.f, 0.f, 0.f};
      za = MFMA(xa0, wih0f[0], za);
      zb = MFMA(xa1, wih0f[1], zb);
#pragma unroll
      for (int kc = 0; kc < 16; ++kc) {
        bf16x8 a = *(const bf16x8*)(sm.a0 + ab + kc * 32);
        if (kc & 1) zb = MFMA(a, *(const bf16x8*)(pwhh0 + kc * 32), zb);
        else        za = MFMA(a, *(const bf16x8*)(pwhh0 + kc * 32), za);
      }
      actstore(za + zb, c0, h0w);
    }
    gbar(slots, g, w, ++ph);

    // ---- phase B: layer1 ----
    {
      stage(sm.a0, h0w);
      stage(sm.a1, h1p);
      __syncthreads();
      f32x4 ya = {b1c, b1c, b1c, b1c}, yb = {0.f, 0.f, 0.f, 0.f};
#pragma unroll
      for (int kc = 0; kc < 16; ++kc) {
        bf16x8 a = *(const bf16x8*)(sm.a0 + ab + kc * 32);
        bf16x8 a2 = *(const bf16x8*)(sm.a1 + ab + kc * 32);
        if (kc & 1) { yb = MFMA(a, *(const bf16x8*)(pwih1 + kc * 32), yb);
                      yb = MFMA(a2, whh1f[kc], yb); }
        else        { ya = MFMA(a, *(const bf16x8*)(pwih1 + kc * 32), ya);
                      ya = MFMA(a2, whh1f[kc], ya); }
      }
      actstore(ya + yb, c1, h1w);
    }
    gbar(slots, g, w, ++ph);

    // ---- phase C: fc for this group's 8 batches, cols w*2 / w*2+1 ----
    {
      stage(sm.a1, h1w);
      __syncthreads();
      int ks = tid >> 4, b = (tid >> 1) & 7, c = tid & 1;
      const unsigned short* hr = sm.a1 + b * PW + ks * 32;
      const unsigned short* wp = sm.wfc2 + c * 512 + ks * 32;
      float s = 0.f;
#pragma unroll
      for (int k2 = 0; k2 < 4; ++k2) {
        bf16x8 hv = *(const bf16x8*)(hr + k2 * 8);
        bf16x8 wv = *(const bf16x8*)(wp + k2 * 8);
#pragma unroll
        for (int q = 0; q < 8; ++q) s += bf2f((unsigned short)hv[q]) * bf2f((unsigned short)wv[q]);
      }
      ((float*)sm.gpart)[tid] = s;
      __syncthreads();
      if (tid < 16) {
        float sv = sm.bfc2[tid & 1];
        const float* fp = (const float*)sm.gpart;
#pragma unroll
        for (int k = 0; k < 16; ++k) sv += fp[k * 16 + tid];
        int bb = tid >> 1, cc = tid & 1;
        out[(size_t)(g * 8 + bb) * (TGT * 64) + d * 64 + (w * 2 + cc)] = sv;
        astf(ybuf + g * 512 + bb * 64 + w * 2 + cc, sv);
      }
    }
    gbar(slots, g, w, ++ph);
  }
}

extern "C" void kernel_launch(void* const* d_in, const int* in_sizes, int n_in,
                              void* d_out, int out_size, void* d_ws, size_t ws_size,
                              hipStream_t stream) {
  (void)in_sizes; (void)n_in; (void)out_size; (void)ws_size;
  const float* x    = (const float*)d_in[0];
  const float* Wih0 = (const float*)d_in[1];
  const float* Whh0 = (const float*)d_in[2];
  const float* bih0 = (const float*)d_in[3];
  const float* bhh0 = (const float*)d_in[4];
  const float* Wih1 = (const float*)d_in[5];
  const float* Whh1 = (const float*)d_in[6];
  const float* bih1 = (const float*)d_in[7];
  const float* bhh1 = (const float*)d_in[8];
  const float* Wfc  = (const float*)d_in[9];
  const float* bfc  = (const float*)d_in[10];

  char* ws = (char*)d_ws;
  unsigned* slots = (unsigned*)ws;                         // 1 KiB (8 groups x 128B)
  u64* h0q   = (u64*)(ws + 1024);                          // 128 KiB (2 slots)
  u64* h1q   = (u64*)(ws + 1024 + 131072);                 // 128 KiB
  float* ybuf = (float*)(ws + 1024 + 262144);              // 16 KiB

  hipMemsetAsync(slots, 0, 1024, stream);
  hipLaunchKernelGGL(lstm_kernel, dim3(NWG), dim3(NTH), 0, stream,
                     x, Wih0, Whh0, bih0, bhh0, Wih1, Whh1, bih1, bhh1, Wfc, bfc,
                     h0q, h1q, ybuf, slots, (float*)d_out);
}

// Round 7
// 2909.741 us; speedup vs baseline: 4.1799x; 1.4614x over previous
//
#include <hip/hip_runtime.h>
#include <stdint.h>

// ---------------------------------------------------------------------------
// LSTM time-series predictor, persistent kernel, R7.
// 8 batch-groups x 32 WGs (g = blockIdx&7, w = blockIdx>>3) — R4-proven roles.
// All cross-WG exchange via RELAXED AGENT-scope atomics (R4-proven; no inline
// asm, no templates, no s_getreg — R5/R6's infra-failing constructs removed).
// Each WG: 16 hidden units of both layers for its group's 8 batches.
// W_hh0/W_ih1 bf16 in LDS, fragment-major [mat][wave][kc][lane][8] ->
// conflict-free ds_read_b128. W_hh1/W_ih0/Wcomb fragments in VGPRs.
// Staged-A LDS: [kc][b][q] with 68-u64 kc stride (conflict-free reads).
// Decoder folded: gates_A(d) = h0_{d-1}@Whh0^T + h1_{d-1}@Wcomb^T + b0d where
// Wcomb = Wih0 @ Wfc (precomputed once into registers), so the fc->feedback
// barrier disappears: 2 barriers/decoder step. out[d-1] computed inside
// phase A'(d) from the staged h1 (no barrier needed; ybuf eliminated).
// Encoder: layer1 lags 1 step -> 513 barriers. Decoder: 2x96 = 192.
// ---------------------------------------------------------------------------

#define NWG 256
#define NTH 256

constexpr int Tt = 512, TGT = 96;

typedef __attribute__((ext_vector_type(8))) short bf16x8;
typedef __attribute__((ext_vector_type(4))) float f32x4;
typedef unsigned long long u64;

__device__ __forceinline__ unsigned short f2bf(float f) {
  union { float f; unsigned u; } v; v.f = f;
  return (unsigned short)((v.u + 0x7fffu + ((v.u >> 16) & 1u)) >> 16);
}
__device__ __forceinline__ float bf2f(unsigned short h) {
  union { unsigned u; float f; } v; v.u = ((unsigned)h) << 16; return v.f;
}
__device__ __forceinline__ float sigm(float x) { return 1.f / (1.f + __expf(-x)); }
__device__ __forceinline__ float tanh_(float x) { return 1.f - 2.f / (__expf(2.f * x) + 1.f); }

__device__ __forceinline__ unsigned ald32a(const unsigned* p) {
  return __hip_atomic_load(p, __ATOMIC_RELAXED, __HIP_MEMORY_SCOPE_AGENT);
}
__device__ __forceinline__ void ast32a(unsigned* p, unsigned v) {
  __hip_atomic_store(p, v, __ATOMIC_RELAXED, __HIP_MEMORY_SCOPE_AGENT);
}
__device__ __forceinline__ u64 ald64a(const u64* p) {
  return __hip_atomic_load(p, __ATOMIC_RELAXED, __HIP_MEMORY_SCOPE_AGENT);
}
__device__ __forceinline__ void ast64a(u64* p, u64 v) {
  __hip_atomic_store(p, v, __ATOMIC_RELAXED, __HIP_MEMORY_SCOPE_AGENT);
}

struct SMem {
  unsigned short wB[2][4][16][64][8]; // 128 KiB: [whh0|wih1][wave][kc][lane][8]
  u64 a0[16 * 68];                    // 8.5 KiB staged A: [kc][b*8 + k8&7]
  u64 a1[16 * 68];                    // 8.5 KiB
  unsigned short wfc2[1024];          // 2 KiB: W_fc rows w*2, w*2+1 (bf16)
  float gpart[4][272];                // per-wave D staging
  float fcp[256];                     // fc partials
  float b0s[64], b1s[64], b0d[64], bfc2[2];
};                                    // ~153 KiB

// staged-A LDS u64 index for global h u64-index idx (b=idx>>7, k8=idx&127)
__device__ __forceinline__ int amap(int idx) {
  int b = idx >> 7, k8 = idx & 127;
  return (k8 >> 3) * 68 + b * 8 + (k8 & 7);
}

__device__ __forceinline__ void stage1(u64* dst, const u64* src, int tid) {
  u64 v0 = ald64a(src + tid),       v1 = ald64a(src + tid + 256);
  u64 v2 = ald64a(src + tid + 512), v3 = ald64a(src + tid + 768);
  dst[amap(tid)] = v0; dst[amap(tid + 256)] = v1;
  dst[amap(tid + 512)] = v2; dst[amap(tid + 768)] = v3;
}
__device__ __forceinline__ void stage2(u64* d0, const u64* s0, u64* d1, const u64* s1, int tid) {
  u64 v0 = ald64a(s0 + tid),       v1 = ald64a(s0 + tid + 256);
  u64 v2 = ald64a(s0 + tid + 512), v3 = ald64a(s0 + tid + 768);
  u64 v4 = ald64a(s1 + tid),       v5 = ald64a(s1 + tid + 256);
  u64 v6 = ald64a(s1 + tid + 512), v7 = ald64a(s1 + tid + 768);
  d0[amap(tid)] = v0; d0[amap(tid + 256)] = v1;
  d0[amap(tid + 512)] = v2; d0[amap(tid + 768)] = v3;
  d1[amap(tid)] = v4; d1[amap(tid + 256)] = v5;
  d1[amap(tid + 512)] = v6; d1[amap(tid + 768)] = v7;
}

// group-scope barrier (32 WGs), R4-proven form
__device__ __forceinline__ void gbar(unsigned* slots, int g, int w, unsigned tgt) {
  __syncthreads();                 // compiler drains vmcnt before s_barrier
  if (threadIdx.x == 0) ast32a(slots + g * 32 + w, tgt);
  if (threadIdx.x < 64) {
    const unsigned* sp = slots + g * 32 + (threadIdx.x & 31);
    while (true) {
      unsigned v = ald32a(sp);
      if (__all((int)(v >= tgt))) break;
      __builtin_amdgcn_s_sleep(1);
    }
  }
  __syncthreads();
}

#define MFMA(a, b, c) __builtin_amdgcn_mfma_f32_16x16x32_bf16(a, b, c, 0, 0, 0)

__global__ __launch_bounds__(NTH, 1) void lstm_kernel(
    const float* __restrict__ x,
    const float* __restrict__ Wih0, const float* __restrict__ Whh0,
    const float* __restrict__ bih0, const float* __restrict__ bhh0,
    const float* __restrict__ Wih1, const float* __restrict__ Whh1,
    const float* __restrict__ bih1, const float* __restrict__ bhh1,
    const float* __restrict__ Wfc, const float* __restrict__ bfc,
    u64* h0q, u64* h1q, unsigned* slots, float* __restrict__ out)
{
  __shared__ SMem sm;
  const int g = blockIdx.x & 7;
  const int wgw = blockIdx.x >> 3;
  const int tid = threadIdx.x;

  // ---- weight staging (fragment-major, conflict-free reads) ----
  for (int e = tid; e < 8192; e += NTH) {   // 2 mats x 4 waves x 16 kc x 64 lanes
    int m = e >> 12, w4 = (e >> 10) & 3, kc = (e >> 6) & 15, l = e & 63;
    int colx = l & 15, qx = l >> 4;
    size_t row = (size_t)((colx & 3) * 512 + wgw * 16 + w4 * 4 + (colx >> 2));
    const float* src = (m ? Wih1 : Whh0) + row * 512 + kc * 32 + qx * 8;
    unsigned short* dst = &sm.wB[m][w4][kc][l][0];
    float4 u = *(const float4*)src, v = *(const float4*)(src + 4);
    dst[0] = f2bf(u.x); dst[1] = f2bf(u.y); dst[2] = f2bf(u.z); dst[3] = f2bf(u.w);
    dst[4] = f2bf(v.x); dst[5] = f2bf(v.y); dst[6] = f2bf(v.z); dst[7] = f2bf(v.w);
  }
  for (int e = tid; e < 1024; e += NTH)
    sm.wfc2[e] = f2bf(Wfc[(size_t)(wgw * 2 + (e >> 9)) * 512 + (e & 511)]);
  if (tid < 64) {
    int jj = tid >> 2, g4 = tid & 3;
    int grow = g4 * 512 + wgw * 16 + jj;
    float s0 = bih0[grow] + bhh0[grow];
    sm.b0s[tid] = s0;
    sm.b1s[tid] = bih1[grow] + bhh1[grow];
    float ex = 0.f;                         // Wih0 row dot bfc (decoder bias)
    for (int i = 0; i < 64; ++i) ex += Wih0[(size_t)grow * 64 + i] * bfc[i];
    sm.b0d[tid] = s0 + ex;
  }
  if (tid < 2) sm.bfc2[tid] = bfc[wgw * 2 + tid];

  // ---- per-lane constants ----
  const int wave = tid >> 6, lane = tid & 63;
  const int col = lane & 15, quad = lane >> 4;
  const int koff = quad * 8;
  const size_t rowg = (size_t)((col & 3) * 512 + wgw * 16 + wave * 4 + (col >> 2));

  // ---- register B-fragments: W_hh1, W_ih0, Wcomb = Wih0 @ Wfc ----
  bf16x8 whh1f[16];
#pragma unroll
  for (int kc = 0; kc < 16; ++kc) {
    const float* p = Whh1 + rowg * 512 + kc * 32 + koff;
    float4 u = *(const float4*)p, v = *(const float4*)(p + 4);
    bf16x8 r;
    r[0] = (short)f2bf(u.x); r[1] = (short)f2bf(u.y); r[2] = (short)f2bf(u.z); r[3] = (short)f2bf(u.w);
    r[4] = (short)f2bf(v.x); r[5] = (short)f2bf(v.y); r[6] = (short)f2bf(v.z); r[7] = (short)f2bf(v.w);
    whh1f[kc] = r;
  }
  bf16x8 wih0f[2];
#pragma unroll
  for (int kc = 0; kc < 2; ++kc) {
    const float* p = Wih0 + rowg * 64 + kc * 32 + koff;
    float4 u = *(const float4*)p, v = *(const float4*)(p + 4);
    bf16x8 r;
    r[0] = (short)f2bf(u.x); r[1] = (short)f2bf(u.y); r[2] = (short)f2bf(u.z); r[3] = (short)f2bf(u.w);
    r[4] = (short)f2bf(v.x); r[5] = (short)f2bf(v.y); r[6] = (short)f2bf(v.z); r[7] = (short)f2bf(v.w);
    wih0f[kc] = r;
  }
  bf16x8 wcombf[16];
  {
    float wc[16][8];
#pragma unroll
    for (int kc = 0; kc < 16; ++kc)
#pragma unroll
      for (int j = 0; j < 8; ++j) wc[kc][j] = 0.f;
    for (int i = 0; i < 64; ++i) {
      float wi = Wih0[rowg * 64 + i];
      const float* fr = Wfc + (size_t)i * 512 + koff;
#pragma unroll
      for (int kc = 0; kc < 16; ++kc) {
        float4 u = *(const float4*)(fr + kc * 32);
        float4 v = *(const float4*)(fr + kc * 32 + 4);
        wc[kc][0] += wi * u.x; wc[kc][1] += wi * u.y;
        wc[kc][2] += wi * u.z; wc[kc][3] += wi * u.w;
        wc[kc][4] += wi * v.x; wc[kc][5] += wi * v.y;
        wc[kc][6] += wi * v.z; wc[kc][7] += wi * v.w;
      }
    }
#pragma unroll
    for (int kc = 0; kc < 16; ++kc) {
      bf16x8 r;
#pragma unroll
      for (int j = 0; j < 8; ++j) r[j] = (short)f2bf(wc[kc][j]);
      wcombf[kc] = r;
    }
  }
  __syncthreads();

  const float b0c = sm.b0s[wave * 16 + col];
  const float b1c = sm.b1s[wave * 16 + col];
  const float b0dc = sm.b0d[wave * 16 + col];
  const unsigned short* pw0 = &sm.wB[0][wave][0][lane][0];   // + kc*512 ushort
  const unsigned short* pw1 = &sm.wB[1][wave][0][lane][0];
  const u64* afrag0 = sm.a0 + (col & 7) * 8 + quad * 2;      // + kc*68
  const u64* afrag1 = sm.a1 + (col & 7) * 8 + quad * 2;
  unsigned ph = 0;
  float c0 = 0.f, c1 = 0.f;
  const size_t xstride = (size_t)Tt * 64;

  auto loadx = [&](const float* p) -> bf16x8 {
    float4 u = *(const float4*)p, v = *(const float4*)(p + 4);
    bf16x8 r;
    r[0] = (short)f2bf(u.x); r[1] = (short)f2bf(u.y); r[2] = (short)f2bf(u.z); r[3] = (short)f2bf(u.w);
    r[4] = (short)f2bf(v.x); r[5] = (short)f2bf(v.y); r[6] = (short)f2bf(v.z); r[7] = (short)f2bf(v.w);
    return r;
  };

  auto actstore = [&](f32x4 v, float& cst, u64* hdst) {
    float* gp = sm.gpart[wave];
#pragma unroll
    for (int r = 0; r < 4; ++r) gp[(quad * 4 + r) * 17 + col] = v[r];
    unsigned hbits = 0;
    int b = lane >> 2, j = lane & 3;
    if (lane < 32) {
      const float* ro = gp + b * 17 + j * 4;
      float iv = sigm(ro[0]), fv = sigm(ro[1]), gv = tanh_(ro[2]), ov = sigm(ro[3]);
      float c = fv * cst + iv * gv; cst = c;
      hbits = f2bf(ov * tanh_(c));
    }
    unsigned h1b = __shfl(hbits, (lane + 1) & 63);
    unsigned h2b = __shfl(hbits, (lane + 2) & 63);
    unsigned h3b = __shfl(hbits, (lane + 3) & 63);
    if (lane < 32 && j == 0) {
      u64 pk = (u64)hbits | ((u64)h1b << 16) | ((u64)h2b << 32) | ((u64)h3b << 48);
      ast64a(hdst + b * 128 + wgw * 4 + wave, pk);
    }
  };

  auto fcpart = [&](const u64* asrc) {      // fc partials from staged h1
    int ks = tid >> 4, b = (tid >> 1) & 7, cc = tid & 1;
    const unsigned short* hr = (const unsigned short*)(asrc + ks * 68 + b * 8);
    const unsigned short* wp = sm.wfc2 + cc * 512 + ks * 32;
    float s = 0.f;
#pragma unroll
    for (int k2 = 0; k2 < 4; ++k2) {
      bf16x8 hv = *(const bf16x8*)(hr + k2 * 8);
      bf16x8 wv = *(const bf16x8*)(wp + k2 * 8);
#pragma unroll
      for (int q2 = 0; q2 < 8; ++q2) s += bf2f((unsigned short)hv[q2]) * bf2f((unsigned short)wv[q2]);
    }
    sm.fcp[tid] = s;
  };
  auto fcout = [&](int d) {                 // reduce + write out[d] (tid<16)
    if (tid < 16) {
      float sv = sm.bfc2[tid & 1];
#pragma unroll
      for (int k = 0; k < 16; ++k) sv += sm.fcp[k * 16 + tid];
      int bb = tid >> 1, cc = tid & 1;
      out[(size_t)(g * 8 + bb) * (TGT * 64) + d * 64 + (wgw * 2 + cc)] = sv;
    }
  };

  // ================= encoder: t = 0..512, layer1 lags by 1 =================
  for (int t = 0; t <= Tt; ++t) {
    const u64* h0prev = h0q + ((t + 1) & 1) * 8192 + g * 1024;
    u64* h0cur = h0q + (t & 1) * 8192 + g * 1024;
    const u64* h1prev = h1q + (t & 1) * 8192 + g * 1024;
    u64* h1cur = h1q + ((t + 1) & 1) * 8192 + g * 1024;

    bf16x8 xa0, xa1;
    if (t < Tt) {
      const float* xb = x + (size_t)(g * 8 + (col & 7)) * xstride + (size_t)t * 64 + koff;
      xa0 = loadx(xb); xa1 = loadx(xb + 32);
    }
    if (t == 1)      { stage1(sm.a0, h0prev, tid); __syncthreads(); }
    else if (t >= 2) { stage2(sm.a0, h0prev, sm.a1, h1prev, tid); __syncthreads(); }

    if (t < Tt) {
      f32x4 za = {b0c, b0c, b0c, b0c}, zb = {0.f, 0.f, 0.f, 0.f};
      za = MFMA(xa0, wih0f[0], za);
      zb = MFMA(xa1, wih0f[1], zb);
      if (t >= 1) {
        f32x4 ya = {b1c, b1c, b1c, b1c}, yb = {0.f, 0.f, 0.f, 0.f};
#pragma unroll
        for (int kc = 0; kc < 16; ++kc) {
          bf16x8 a = *(const bf16x8*)(afrag0 + kc * 68);
          bf16x8 w0 = *(const bf16x8*)(pw0 + kc * 512);
          bf16x8 w1 = *(const bf16x8*)(pw1 + kc * 512);
          if (kc & 1) { zb = MFMA(a, w0, zb); yb = MFMA(a, w1, yb); }
          else        { za = MFMA(a, w0, za); ya = MFMA(a, w1, ya); }
        }
        if (t >= 2) {
#pragma unroll
          for (int kc = 0; kc < 16; ++kc) {
            bf16x8 a = *(const bf16x8*)(afrag1 + kc * 68);
            if (kc & 1) yb = MFMA(a, whh1f[kc], yb);
            else        ya = MFMA(a, whh1f[kc], ya);
          }
        }
        actstore(za + zb, c0, h0cur);
        actstore(ya + yb, c1, h1cur);
      } else {
        actstore(za + zb, c0, h0cur);
      }
    } else {                                   // t == Tt: final layer1 step
      f32x4 ya = {b1c, b1c, b1c, b1c}, yb = {0.f, 0.f, 0.f, 0.f};
#pragma unroll
      for (int kc = 0; kc < 16; ++kc) {
        bf16x8 a = *(const bf16x8*)(afrag0 + kc * 68);
        bf16x8 w1 = *(const bf16x8*)(pw1 + kc * 512);
        if (kc & 1) yb = MFMA(a, w1, yb);
        else        ya = MFMA(a, w1, ya);
      }
#pragma unroll
      for (int kc = 0; kc < 16; ++kc) {
        bf16x8 a = *(const bf16x8*)(afrag1 + kc * 68);
        if (kc & 1) yb = MFMA(a, whh1f[kc], yb);
        else        ya = MFMA(a, whh1f[kc], ya);
      }
      actstore(ya + yb, c1, h1cur);
    }
    gbar(slots, g, wgw, ++ph);
  }

  // ================= decoder =================
  // d=0, phase A (real x input):
  {
    stage2(sm.a0, h0q + 8192 + g * 1024, sm.a1, h1q + 8192 + g * 1024, tid);
    __syncthreads();
    const float* xb = x + (size_t)(g * 8 + (col & 7)) * xstride + (size_t)(Tt - 1) * 64 + koff;
    bf16x8 xa0 = loadx(xb), xa1 = loadx(xb + 32);
    f32x4 za = {b0c, b0c, b0c, b0c}, zb = {0.f, 0.f, 0.f, 0.f};
    za = MFMA(xa0, wih0f[0], za);
    zb = MFMA(xa1, wih0f[1], zb);
#pragma unroll
    for (int kc = 0; kc < 16; ++kc) {
      bf16x8 a = *(const bf16x8*)(afrag0 + kc * 68);
      bf16x8 w0 = *(const bf16x8*)(pw0 + kc * 512);
      if (kc & 1) zb = MFMA(a, w0, zb);
      else        za = MFMA(a, w0, za);
    }
    actstore(za + zb, c0, h0q + g * 1024);          // slot 0
  }
  gbar(slots, g, wgw, ++ph);
  // d=0, phase B (a1 still holds h1_enc_last):
  {
    stage1(sm.a0, h0q + g * 1024, tid);
    __syncthreads();
    f32x4 ya = {b1c, b1c, b1c, b1c}, yb = {0.f, 0.f, 0.f, 0.f};
#pragma unroll
    for (int kc = 0; kc < 16; ++kc) {
      bf16x8 a = *(const bf16x8*)(afrag0 + kc * 68);
      bf16x8 w1 = *(const bf16x8*)(pw1 + kc * 512);
      bf16x8 a2 = *(const bf16x8*)(afrag1 + kc * 68);
      if (kc & 1) { yb = MFMA(a, w1, yb); yb = MFMA(a2, whh1f[kc], yb); }
      else        { ya = MFMA(a, w1, ya); ya = MFMA(a2, whh1f[kc], ya); }
    }
    actstore(ya + yb, c1, h1q + g * 1024);          // slot 0
  }
  gbar(slots, g, wgw, ++ph);

  for (int d = 1; d < TGT; ++d) {
    // phase A': layer0 with folded fc feedback (Wcomb), + out[d-1]
    {
      stage2(sm.a0, h0q + ((d + 1) & 1) * 8192 + g * 1024,
             sm.a1, h1q + ((d + 1) & 1) * 8192 + g * 1024, tid);
      __syncthreads();
      fcpart(sm.a1);                                 // y_{d-1} partials
      f32x4 za = {b0dc, b0dc, b0dc, b0dc}, zb = {0.f, 0.f, 0.f, 0.f};
#pragma unroll
      for (int kc = 0; kc < 16; ++kc) {
        bf16x8 a = *(const bf16x8*)(afrag0 + kc * 68);
        bf16x8 w0 = *(const bf16x8*)(pw0 + kc * 512);
        bf16x8 a2 = *(const bf16x8*)(afrag1 + kc * 68);
        if (kc & 1) { zb = MFMA(a, w0, zb); zb = MFMA(a2, wcombf[kc], zb); }
        else        { za = MFMA(a, w0, za); za = MFMA(a2, wcombf[kc], za); }
      }
      actstore(za + zb, c0, h0q + (d & 1) * 8192 + g * 1024);
      __syncthreads();
      fcout(d - 1);
    }
    gbar(slots, g, wgw, ++ph);

    // phase B: layer1 (a1 still holds h1_{d-1})
    {
      stage1(sm.a0, h0q + (d & 1) * 8192 + g * 1024, tid);
      __syncthreads();
      f32x4 ya = {b1c, b1c, b1c, b1c}, yb = {0.f, 0.f, 0.f, 0.f};
#pragma unroll
      for (int kc = 0; kc < 16; ++kc) {
        bf16x8 a = *(const bf16x8*)(afrag0 + kc * 68);
        bf16x8 w1 = *(const bf16x8*)(pw1 + kc * 512);
        bf16x8 a2 = *(const bf16x8*)(afrag1 + kc * 68);
        if (kc & 1) { yb = MFMA(a, w1, yb); yb = MFMA(a2, whh1f[kc], yb); }
        else        { ya = MFMA(a, w1, ya); ya = MFMA(a2, whh1f[kc], ya); }
      }
      actstore(ya + yb, c1, h1q + (d & 1) * 8192 + g * 1024);
    }
    gbar(slots, g, wgw, ++ph);
  }

  // final fc: out[95] from h1_95 (slot 1)
  {
    stage1(sm.a1, h1q + 8192 + g * 1024, tid);
    __syncthreads();
    fcpart(sm.a1);
    __syncthreads();
    fcout(TGT - 1);
  }
}

extern "C" void kernel_launch(void* const* d_in, const int* in_sizes, int n_in,
                              void* d_out, int out_size, void* d_ws, size_t ws_size,
                              hipStream_t stream) {
  (void)in_sizes; (void)n_in; (void)out_size; (void)ws_size;
  const float* x    = (const float*)d_in[0];
  const float* Wih0 = (const float*)d_in[1];
  const float* Whh0 = (const float*)d_in[2];
  const float* bih0 = (const float*)d_in[3];
  const float* bhh0 = (const float*)d_in[4];
  const float* Wih1 = (const float*)d_in[5];
  const float* Whh1 = (const float*)d_in[6];
  const float* bih1 = (const float*)d_in[7];
  const float* bhh1 = (const float*)d_in[8];
  const float* Wfc  = (const float*)d_in[9];
  const float* bfc  = (const float*)d_in[10];

  char* ws = (char*)d_ws;
  unsigned* slots = (unsigned*)ws;                        // 1 KiB (8 groups x 128B)
  u64* h0q = (u64*)(ws + 2048);                           // 128 KiB (2 slots)
  u64* h1q = (u64*)(ws + 2048 + 131072);                  // 128 KiB

  hipMemsetAsync(slots, 0, 2048, stream);
  hipLaunchKernelGGL(lstm_kernel, dim3(NWG), dim3(NTH), 0, stream,
                     x, Wih0, Whh0, bih0, bhh0, Wih1, Whh1, bih1, bhh1, Wfc, bfc,
                     h0q, h1q, slots, (float*)d_out);
}